// Round 3
// baseline (473.163 us; speedup 1.0000x reference)
//
#include <hip/hip_runtime.h>
#include <hip/hip_bf16.h>

typedef unsigned int uint;

#define N_TOK 4096        // B*T
#define EMB_D 64
#define NEG_K 512
#define LOGITS_W 513
#define NROWS 1000000
#define NREC (N_TOK * NEG_K)      // 2,097,152
#define NC4  (NROWS / 4)          // 250,000 uint4 count-chunks
#define NB1  ((NC4 + 255) / 256)  // 977 scan blocks

// ---- ws layout (byte offsets) ----
#define X_OFF   (0u)
#define CNT_OFF (1u << 20)
#define OFS_OFF (5u << 20)
#define CUR_OFF (9u << 20)
#define BS_OFF  (13u << 20)
#define REC_OFF (14u << 20)
#define WS_NEED (23u << 20)

// ---------------------------------------------------------------------------
// Projection x = embeds @ W + b; zero loss; zero counts (if provided).
// ---------------------------------------------------------------------------
__global__ __launch_bounds__(256) void proj_kernel(
    const float* __restrict__ embeds, const float* __restrict__ W,
    const float* __restrict__ b, float* __restrict__ x,
    float* __restrict__ loss, uint* __restrict__ counts)
{
    __shared__ float Ws[EMB_D][EMB_D];
    __shared__ float Es[4][EMB_D];
    const int tid = threadIdx.x;
    const int n0 = blockIdx.x * 4;

    if (counts) {                       // zero 1M counters as uint4
        const int ci = blockIdx.x * 256 + tid;   // 1024*256 = 262144 >= 250000
        if (ci < NC4) ((uint4*)counts)[ci] = make_uint4(0, 0, 0, 0);
    }

    for (int i = tid; i < EMB_D * EMB_D; i += 256)
        Ws[i >> 6][i & 63] = W[i];
    for (int i = tid; i < 4 * EMB_D; i += 256)
        Es[i >> 6][i & 63] = embeds[(size_t)n0 * EMB_D + i];
    __syncthreads();

    const int nl = tid >> 6;
    const int e  = tid & 63;
    float acc = b[e];
    #pragma unroll
    for (int d = 0; d < EMB_D; ++d)
        acc += Es[nl][d] * Ws[d][e];
    x[(size_t)(n0 + nl) * EMB_D + e] = acc;

    if (blockIdx.x == 0 && tid == 0) loss[0] = 0.0f;
}

// ---------------------------------------------------------------------------
// Histogram: counts[idx]++ over all 2.1M negative samples.
// ---------------------------------------------------------------------------
__global__ __launch_bounds__(256) void hist_kernel(
    const int* __restrict__ neg, uint* __restrict__ counts)
{
    const int i = blockIdx.x * 256 + threadIdx.x;   // grid 2048 -> 524288 = NREC/4
    const int4 v = ((const int4*)neg)[i];
    atomicAdd(&counts[v.x], 1u);
    atomicAdd(&counts[v.y], 1u);
    atomicAdd(&counts[v.z], 1u);
    atomicAdd(&counts[v.w], 1u);
}

// ---------------------------------------------------------------------------
// Scan stage 1: per-block (1024 counts) sums.
// ---------------------------------------------------------------------------
__global__ __launch_bounds__(256) void scan1_kernel(
    const uint* __restrict__ counts, uint* __restrict__ bsums)
{
    __shared__ uint lds[4];
    const int t = threadIdx.x;
    const int i = blockIdx.x * 256 + t;
    uint s = 0;
    if (i < NC4) { uint4 c = ((const uint4*)counts)[i]; s = c.x + c.y + c.z + c.w; }
    #pragma unroll
    for (int o = 32; o > 0; o >>= 1) s += __shfl_xor(s, o);
    if ((t & 63) == 0) lds[t >> 6] = s;
    __syncthreads();
    if (t == 0) bsums[blockIdx.x] = lds[0] + lds[1] + lds[2] + lds[3];
}

// ---------------------------------------------------------------------------
// Scan stage 2: exclusive scan of the 977 block sums (single block).
// ---------------------------------------------------------------------------
__global__ __launch_bounds__(256) void scan2_kernel(uint* __restrict__ bsums)
{
    __shared__ uint wsum[4];
    const int t = threadIdx.x, lane = t & 63, w = t >> 6;
    uint a0 = 0, a1 = 0, a2 = 0, a3 = 0;
    if (4 * t     < NB1) a0 = bsums[4 * t];
    if (4 * t + 1 < NB1) a1 = bsums[4 * t + 1];
    if (4 * t + 2 < NB1) a2 = bsums[4 * t + 2];
    if (4 * t + 3 < NB1) a3 = bsums[4 * t + 3];
    const uint s = a0 + a1 + a2 + a3;
    uint incl = s;
    #pragma unroll
    for (int o = 1; o < 64; o <<= 1) { uint u = __shfl_up(incl, o); if (lane >= o) incl += u; }
    if (lane == 63) wsum[w] = incl;
    __syncthreads();
    uint wb = 0;
    for (int ww = 0; ww < w; ++ww) wb += wsum[ww];
    const uint excl = wb + incl - s;
    if (4 * t     < NB1) bsums[4 * t]     = excl;
    if (4 * t + 1 < NB1) bsums[4 * t + 1] = excl + a0;
    if (4 * t + 2 < NB1) bsums[4 * t + 2] = excl + a0 + a1;
    if (4 * t + 3 < NB1) bsums[4 * t + 3] = excl + a0 + a1 + a2;
}

// ---------------------------------------------------------------------------
// Scan stage 3: per-element exclusive offsets = block base + local scan.
// Writes offsets AND a second copy used as atomic cursors.
// ---------------------------------------------------------------------------
__global__ __launch_bounds__(256) void scan3_kernel(
    const uint* __restrict__ counts, const uint* __restrict__ bsums,
    uint* __restrict__ offsets, uint* __restrict__ cursors)
{
    __shared__ uint wsum[4];
    const int t = threadIdx.x, lane = t & 63, w = t >> 6;
    const int i = blockIdx.x * 256 + t;
    uint4 c = make_uint4(0, 0, 0, 0);
    if (i < NC4) c = ((const uint4*)counts)[i];
    const uint s = c.x + c.y + c.z + c.w;
    uint incl = s;
    #pragma unroll
    for (int o = 1; o < 64; o <<= 1) { uint u = __shfl_up(incl, o); if (lane >= o) incl += u; }
    if (lane == 63) wsum[w] = incl;
    __syncthreads();
    uint wb = 0;
    for (int ww = 0; ww < w; ++ww) wb += wsum[ww];
    const uint base = bsums[blockIdx.x] + wb + incl - s;
    if (i < NC4) {
        uint4 o4;
        o4.x = base;
        o4.y = o4.x + c.x;
        o4.z = o4.y + c.y;
        o4.w = o4.z + c.z;
        ((uint4*)offsets)[i] = o4;
        ((uint4*)cursors)[i] = o4;
    }
}

// ---------------------------------------------------------------------------
// Scatter: records[slot] = flat ref id m (n = m>>9, k = m&511), CSR by class.
// ---------------------------------------------------------------------------
__global__ __launch_bounds__(256) void scatter_kernel(
    const int* __restrict__ neg, uint* __restrict__ cursors,
    uint* __restrict__ records)
{
    const int i = blockIdx.x * 256 + threadIdx.x;   // grid 2048
    const int4 v = ((const int4*)neg)[i];
    const uint m = (uint)i * 4u;
    uint s0 = atomicAdd(&cursors[v.x], 1u); records[s0] = m;
    uint s1 = atomicAdd(&cursors[v.y], 1u); records[s1] = m + 1;
    uint s2 = atomicAdd(&cursors[v.z], 1u); records[s2] = m + 2;
    uint s3 = atomicAdd(&cursors[v.w], 1u); records[s3] = m + 3;
}

// ---------------------------------------------------------------------------
// Stream pass: sequentially sweep the table; for each referenced row compute
// dots against x (L2-resident) and scatter scores into logits.
// 16-lane group per row chunk; group g owns rows [16g, 16g+16).
// ---------------------------------------------------------------------------
__global__ __launch_bounds__(512) void stream_kernel(
    const float* __restrict__ table, const float* __restrict__ x,
    const uint* __restrict__ counts, const uint* __restrict__ offsets,
    const uint* __restrict__ records, float* __restrict__ logits)
{
    const int gid = (blockIdx.x * 512 + threadIdx.x) >> 4;
    const int l   = threadIdx.x & 15;
    const int r0  = gid * 16;
    if (r0 >= NROWS) return;

    uint c_l = 0, o_l = 0;
    { const int rr = r0 + l; if (rr < NROWS) { c_l = counts[rr]; o_l = offsets[rr]; } }

    const float4* t4 = (const float4*)table;
    const float4* x4 = (const float4*)x;

    for (int q = 0; q < 16; ++q) {
        const int r = r0 + q;
        const uint c = __shfl(c_l, q, 16);
        if (c == 0) continue;
        const uint off = __shfl(o_l, q, 16);
        const float4 rv = t4[(size_t)r * 16 + l];
        for (uint j = 0; j < c; ++j) {
            const uint rec = records[off + j];
            const uint n = rec >> 9, k = rec & 511u;
            const float4 xv = x4[n * 16 + l];
            float s = rv.x * xv.x + rv.y * xv.y + rv.z * xv.z + rv.w * xv.w;
            s += __shfl_xor(s, 8, 16);
            s += __shfl_xor(s, 4, 16);
            s += __shfl_xor(s, 2, 16);
            s += __shfl_xor(s, 1, 16);
            if (l == 0) logits[(size_t)n * LOGITS_W + 1 + k] = s;
        }
    }
}

// ---------------------------------------------------------------------------
// Final pass: positive score + logsumexp + loss. One block per token.
// ---------------------------------------------------------------------------
__global__ __launch_bounds__(512) void lse_kernel(
    const float* __restrict__ x, const int* __restrict__ labels,
    const float* __restrict__ table, float* __restrict__ logits,
    float* __restrict__ loss)
{
    const int n = blockIdx.x, tid = threadIdx.x;
    __shared__ float red[8];
    __shared__ float posS, Ms;

    if (tid < 16) {
        const int pidx = labels[n];
        const float4 rv = ((const float4*)table)[(size_t)pidx * 16 + tid];
        const float4 xv = ((const float4*)x)[n * 16 + tid];
        float p = rv.x * xv.x + rv.y * xv.y + rv.z * xv.z + rv.w * xv.w;
        p += __shfl_xor(p, 8, 16);
        p += __shfl_xor(p, 4, 16);
        p += __shfl_xor(p, 2, 16);
        p += __shfl_xor(p, 1, 16);
        if (tid == 0) { posS = p; logits[(size_t)n * LOGITS_W] = p; }
    }
    __syncthreads();
    const float pos = posS;
    const float v = logits[(size_t)n * LOGITS_W + 1 + tid];

    float m = (tid == 0) ? fmaxf(v, pos) : v;
    #pragma unroll
    for (int o = 32; o > 0; o >>= 1) m = fmaxf(m, __shfl_xor(m, o));
    if ((tid & 63) == 0) red[tid >> 6] = m;
    __syncthreads();
    if (tid == 0) {
        float mm = red[0];
        #pragma unroll
        for (int w = 1; w < 8; ++w) mm = fmaxf(mm, red[w]);
        Ms = mm;
    }
    __syncthreads();
    const float M = Ms;

    float e = expf(v - M);
    #pragma unroll
    for (int o = 32; o > 0; o >>= 1) e += __shfl_xor(e, o);
    __syncthreads();
    if ((tid & 63) == 0) red[tid >> 6] = e;
    __syncthreads();
    if (tid == 0) {
        float s = expf(pos - M);
        #pragma unroll
        for (int w = 0; w < 8; ++w) s += red[w];
        const float lse = M + logf(s);
        atomicAdd(loss, (lse - pos) * (1.0f / (float)N_TOK));
    }
}

// ---------------------------------------------------------------------------
// Fallback (small ws): R1-style direct gather per token.
// ---------------------------------------------------------------------------
__global__ __launch_bounds__(512) void score_fallback(
    const float* __restrict__ x, const int* __restrict__ labels,
    const int* __restrict__ neg, const float* __restrict__ table,
    float* __restrict__ logits, float* __restrict__ loss)
{
    const int n = blockIdx.x, tid = threadIdx.x;
    __shared__ float xs[EMB_D];
    __shared__ float red[8];
    __shared__ float posS, Ms;
    if (tid < EMB_D) xs[tid] = x[(size_t)n * EMB_D + tid];
    __syncthreads();
    const float4* xv = (const float4*)xs;
    const int idx = neg[(size_t)n * NEG_K + tid];
    const float4* row = (const float4*)(table + (size_t)idx * EMB_D);
    float acc = 0.0f;
    #pragma unroll
    for (int j = 0; j < 16; ++j) {
        float4 r = row[j]; float4 u = xv[j];
        acc += r.x * u.x + r.y * u.y + r.z * u.z + r.w * u.w;
    }
    logits[(size_t)n * LOGITS_W + 1 + tid] = acc;
    if (tid < 16) {
        const int pidx = labels[n];
        const float4 r = ((const float4*)(table + (size_t)pidx * EMB_D))[tid];
        const float4 u = xv[tid];
        float p = r.x * u.x + r.y * u.y + r.z * u.z + r.w * u.w;
        #pragma unroll
        for (int o = 8; o > 0; o >>= 1) p += __shfl_xor(p, o, 16);
        if (tid == 0) { posS = p; logits[(size_t)n * LOGITS_W] = p; }
    }
    __syncthreads();
    const float pos = posS;
    float m = acc;
    #pragma unroll
    for (int o = 32; o > 0; o >>= 1) m = fmaxf(m, __shfl_xor(m, o));
    if ((tid & 63) == 0) red[tid >> 6] = m;
    __syncthreads();
    if (tid == 0) {
        float mm = pos;
        #pragma unroll
        for (int w = 0; w < 8; ++w) mm = fmaxf(mm, red[w]);
        Ms = mm;
    }
    __syncthreads();
    const float M = Ms;
    float e = expf(acc - M);
    #pragma unroll
    for (int o = 32; o > 0; o >>= 1) e += __shfl_xor(e, o);
    __syncthreads();
    if ((tid & 63) == 0) red[tid >> 6] = e;
    __syncthreads();
    if (tid == 0) {
        float s = expf(pos - M);
        #pragma unroll
        for (int w = 0; w < 8; ++w) s += red[w];
        atomicAdd(loss, (M + logf(s) - pos) * (1.0f / (float)N_TOK));
    }
}

extern "C" void kernel_launch(void* const* d_in, const int* in_sizes, int n_in,
                              void* d_out, int out_size, void* d_ws, size_t ws_size,
                              hipStream_t stream) {
    const float* embeds = (const float*)d_in[0];
    const int*   labels = (const int*)d_in[1];
    const int*   neg    = (const int*)d_in[2];
    const float* proj_w = (const float*)d_in[3];
    const float* proj_b = (const float*)d_in[4];
    const float* table  = (const float*)d_in[5];

    float* logits = (float*)d_out;
    float* loss   = (float*)d_out + (size_t)N_TOK * LOGITS_W;

    char* ws = (char*)d_ws;
    float* x = (float*)(ws + X_OFF);

    if (ws_size >= WS_NEED) {
        uint* counts  = (uint*)(ws + CNT_OFF);
        uint* offsets = (uint*)(ws + OFS_OFF);
        uint* cursors = (uint*)(ws + CUR_OFF);
        uint* bsums   = (uint*)(ws + BS_OFF);
        uint* records = (uint*)(ws + REC_OFF);

        proj_kernel<<<N_TOK / 4, 256, 0, stream>>>(embeds, proj_w, proj_b, x, loss, counts);
        hist_kernel<<<NREC / 1024, 256, 0, stream>>>(neg, counts);
        scan1_kernel<<<NB1, 256, 0, stream>>>(counts, bsums);
        scan2_kernel<<<1, 256, 0, stream>>>(bsums);
        scan3_kernel<<<NB1, 256, 0, stream>>>(counts, bsums, offsets, cursors);
        scatter_kernel<<<NREC / 1024, 256, 0, stream>>>(neg, cursors, records);
        stream_kernel<<<(NROWS / 16 + 31) / 32, 512, 0, stream>>>(table, x, counts, offsets, records, logits);
        lse_kernel<<<N_TOK, 512, 0, stream>>>(x, labels, table, logits, loss);
    } else {
        proj_kernel<<<N_TOK / 4, 256, 0, stream>>>(embeds, proj_w, proj_b, x, loss, (uint*)nullptr);
        score_fallback<<<N_TOK, 512, 0, stream>>>(x, labels, neg, table, logits, loss);
    }
}

// Round 4
// 105.454 us; speedup vs baseline: 4.4869x; 4.4869x over previous
//
#include <hip/hip_runtime.h>
#include <hip/hip_bf16.h>

#define N_TOK 4096        // B*T = 32*128
#define EMB_D 64
#define NEG_K 512
#define LOGITS_W 513      // 1 + NEG_K

// ws layout: x [4096*64 f32] | partials [4096 f32]
#define X_OFF    0
#define PART_OFF (N_TOK * EMB_D)

// ---------------------------------------------------------------------------
// Kernel 1: projection x = embeds @ W + b.
// ---------------------------------------------------------------------------
__global__ __launch_bounds__(256) void proj_kernel(
    const float* __restrict__ embeds,
    const float* __restrict__ W,
    const float* __restrict__ b,
    float* __restrict__ x)
{
    __shared__ float Ws[EMB_D][EMB_D];   // 16 KB
    __shared__ float Es[4][EMB_D];
    const int tid = threadIdx.x;
    const int n0 = blockIdx.x * 4;

    for (int i = tid; i < EMB_D * EMB_D; i += 256)
        Ws[i >> 6][i & 63] = W[i];
    for (int i = tid; i < 4 * EMB_D; i += 256)
        Es[i >> 6][i & 63] = embeds[(size_t)n0 * EMB_D + i];
    __syncthreads();

    const int nl = tid >> 6;    // local row 0..3
    const int e  = tid & 63;    // output dim
    float acc = b[e];
    #pragma unroll
    for (int d = 0; d < EMB_D; ++d)
        acc += Es[nl][d] * Ws[d][e];
    x[(size_t)(n0 + nl) * EMB_D + e] = acc;
}

// ---------------------------------------------------------------------------
// Kernel 2: per-token scoring + logits + per-block loss partial.
// One block of 512 threads per token; thread k gathers negative row k
// (16 independent float4 loads, 4-line L1 reuse), x broadcast from LDS.
// This structure is lookup-optimal: 8.4M random table-line lookups, x free.
// ---------------------------------------------------------------------------
__global__ __launch_bounds__(512) void score_kernel(
    const float* __restrict__ x,        // [N,64]
    const int*   __restrict__ labels,   // [N]
    const int*   __restrict__ neg,      // [N,512]
    const float* __restrict__ table,    // [1e6,64]
    float* __restrict__ logits,         // [N,513]
    float* __restrict__ partials)       // [N]
{
    const int n   = blockIdx.x;
    const int tid = threadIdx.x;

    __shared__ float xs[EMB_D];
    __shared__ float red[8];
    __shared__ float posS;
    __shared__ float Ms;

    if (tid < EMB_D) xs[tid] = x[(size_t)n * EMB_D + tid];
    __syncthreads();

    const float4* xv = (const float4*)xs;

    // ---- negative score: thread tid -> negative tid ----
    const int idx = neg[(size_t)n * NEG_K + tid];
    const float4* row = (const float4*)(table + (size_t)idx * EMB_D);
    float acc = 0.0f;
    #pragma unroll
    for (int j = 0; j < 16; ++j) {
        float4 r = row[j];
        float4 v = xv[j];        // LDS broadcast
        acc += r.x * v.x + r.y * v.y + r.z * v.z + r.w * v.w;
    }
    logits[(size_t)n * LOGITS_W + 1 + tid] = acc;

    // ---- positive score: lanes 0..15 of wave 0 ----
    if (tid < 16) {
        const int pidx = labels[n];
        const float4 r = ((const float4*)(table + (size_t)pidx * EMB_D))[tid];
        const float4 v = xv[tid];
        float p = r.x * v.x + r.y * v.y + r.z * v.z + r.w * v.w;
        #pragma unroll
        for (int o = 8; o > 0; o >>= 1) p += __shfl_xor(p, o, 16);
        if (tid == 0) {
            posS = p;
            logits[(size_t)n * LOGITS_W] = p;
        }
    }
    __syncthreads();
    const float pos = posS;

    // ---- block max over {pos, 512 negs} ----
    float m = acc;
    #pragma unroll
    for (int o = 32; o > 0; o >>= 1) m = fmaxf(m, __shfl_xor(m, o));
    const int wave = tid >> 6;
    if ((tid & 63) == 0) red[wave] = m;
    __syncthreads();
    if (tid == 0) {
        float mm = pos;
        #pragma unroll
        for (int w = 0; w < 8; ++w) mm = fmaxf(mm, red[w]);
        Ms = mm;
    }
    __syncthreads();
    const float M = Ms;

    // ---- block sum of exp ----
    float e = expf(acc - M);
    #pragma unroll
    for (int o = 32; o > 0; o >>= 1) e += __shfl_xor(e, o);
    __syncthreads();             // red[] reads from max pass complete
    if ((tid & 63) == 0) red[wave] = e;
    __syncthreads();
    if (tid == 0) {
        float s = expf(pos - M);
        #pragma unroll
        for (int w = 0; w < 8; ++w) s += red[w];
        const float lse = M + logf(s);
        partials[n] = lse - pos;     // no atomics: deterministic, no tail
    }
}

// ---------------------------------------------------------------------------
// Kernel 3: loss = mean(partials). One block, 512 threads, 8 values each.
// ---------------------------------------------------------------------------
__global__ __launch_bounds__(512) void loss_kernel(
    const float* __restrict__ partials, float* __restrict__ loss)
{
    __shared__ float red[8];
    const int tid = threadIdx.x;
    float s = 0.0f;
    #pragma unroll
    for (int i = 0; i < 8; ++i)
        s += partials[tid + i * 512];
    #pragma unroll
    for (int o = 32; o > 0; o >>= 1) s += __shfl_xor(s, o);
    if ((tid & 63) == 0) red[tid >> 6] = s;
    __syncthreads();
    if (tid == 0) {
        float t = 0.0f;
        #pragma unroll
        for (int w = 0; w < 8; ++w) t += red[w];
        loss[0] = t * (1.0f / (float)N_TOK);
    }
}

extern "C" void kernel_launch(void* const* d_in, const int* in_sizes, int n_in,
                              void* d_out, int out_size, void* d_ws, size_t ws_size,
                              hipStream_t stream) {
    const float* embeds = (const float*)d_in[0];   // [32,128,64]
    const int*   labels = (const int*)d_in[1];     // [4096]
    const int*   neg    = (const int*)d_in[2];     // [4096,512]
    const float* proj_w = (const float*)d_in[3];   // [64,64]
    const float* proj_b = (const float*)d_in[4];   // [64]
    const float* table  = (const float*)d_in[5];   // [1e6,64]

    float* logits   = (float*)d_out;                             // [4096,513]
    float* loss     = (float*)d_out + (size_t)N_TOK * LOGITS_W;  // [1]
    float* x        = (float*)d_ws + X_OFF;                      // [4096,64]
    float* partials = (float*)d_ws + PART_OFF;                   // [4096]

    proj_kernel<<<N_TOK / 4, 256, 0, stream>>>(embeds, proj_w, proj_b, x);
    score_kernel<<<N_TOK, 512, 0, stream>>>(x, labels, neg, table, logits, partials);
    loss_kernel<<<1, 512, 0, stream>>>(partials, loss);
}